// Round 17
// baseline (121.922 us; speedup 1.0000x reference)
//
#include <hip/hip_runtime.h>
#include <cstdint>
#include <cstddef>

typedef __bf16 bf16x8 __attribute__((ext_vector_type(8)));
typedef float f32x4 __attribute__((ext_vector_type(4)));
typedef unsigned short us4 __attribute__((ext_vector_type(4)));
typedef unsigned short us8 __attribute__((ext_vector_type(8)));
typedef unsigned int ui4 __attribute__((ext_vector_type(4)));
typedef unsigned short u16;

// 0.125 (1/sqrt(Dh)) * log2(e) -- Q prescale so softmax uses raw v_exp_f32 (exp2)
#define QSCALE 0.18033688011112042f

#define MFMA16(a, b, c) __builtin_amdgcn_mfma_f32_16x16x32_bf16((a), (b), (c), 0, 0, 0)
#define GLOAD16(g, l)                                                        \
  __builtin_amdgcn_global_load_lds(                                          \
      (const __attribute__((address_space(1))) void*)(g),                    \
      (__attribute__((address_space(3))) void*)(l), 16, 0, 0)

__device__ __forceinline__ u16 f2bf(float x) {
  unsigned int u = __float_as_uint(x);
  unsigned int r = u + 0x7fffu + ((u >> 16) & 1u);
  return (u16)(r >> 16);
}

// ------------------------------------------------- fused LayerNorm + wprep
// blocks 0..4095: LN row; blocks 4096..6143: weight convert (4 mats x 512).
__global__ __launch_bounds__(256) void prep_kernel(
    const float* __restrict__ x, const float* __restrict__ wq,
    const float* __restrict__ wk, const float* __restrict__ wv,
    const float* __restrict__ wo, u16* __restrict__ xn,
    u16* __restrict__ wdst) {
  const int bid = blockIdx.x;
  const int t = threadIdx.x;
  if (bid < 4096) {
    const int row = bid;
    const float* xr = x + (size_t)row * 1024;
    float4 v = *(const float4*)(xr + t * 4);
    float s = v.x + v.y + v.z + v.w;
    float s2 = v.x * v.x + v.y * v.y + v.z * v.z + v.w * v.w;
#pragma unroll
    for (int o = 32; o >= 1; o >>= 1) {
      s += __shfl_xor(s, o);
      s2 += __shfl_xor(s2, o);
    }
    __shared__ float red[8];
    const int wv_ = t >> 6, ln = t & 63;
    if (ln == 0) {
      red[wv_] = s;
      red[4 + wv_] = s2;
    }
    __syncthreads();
    s = red[0] + red[1] + red[2] + red[3];
    s2 = red[4] + red[5] + red[6] + red[7];
    const float mu = s * (1.0f / 1024.0f);
    float var = (s2 - 1024.0f * mu * mu) * (1.0f / 1023.0f);
    var = fmaxf(var, 0.0f);
    const float inv = 1.0f / (sqrtf(var) + 1e-6f);
    us4 o;
    o.x = f2bf((v.x - mu) * inv);
    o.y = f2bf((v.y - mu) * inv);
    o.z = f2bf((v.z - mu) * inv);
    o.w = f2bf((v.w - mu) * inv);
    *(us4*)(xn + (size_t)row * 1024 + t * 4) = o;
  } else {
    const int wid = bid - 4096;
    const int mat = wid >> 9, xi = wid & 511;
    const float* src = (mat == 0) ? wq : (mat == 1) ? wk : (mat == 2) ? wv : wo;
    const float sc = (mat == 0) ? QSCALE : 1.0f;
    u16* d = wdst + ((size_t)mat << 20);
    const size_t i = ((size_t)xi * 256 + t) * 8;
    float4 a = *(const float4*)(src + i);
    float4 b = *(const float4*)(src + i + 4);
    us8 o;
    o[0] = f2bf(a.x * sc);
    o[1] = f2bf(a.y * sc);
    o[2] = f2bf(a.z * sc);
    o[3] = f2bf(a.w * sc);
    o[4] = f2bf(b.x * sc);
    o[5] = f2bf(b.y * sc);
    o[6] = f2bf(b.z * sc);
    o[7] = f2bf(b.w * sc);
    *(us8*)(d + i) = o;
  }
}

// ------------------------------------------- GEMM core (R16-proven BK=64)
// C[64x128] = A[64xK] * W[128xK]^T. Fat-step dbuf-2 + __syncthreads:
// 16 steps of 16 MFMAs + 12 ds_reads per wave. 48 KB LDS.
// Swizzle: 128-B rows, source chunk c^(r&7), read chunk (ks*4+lg)^(lr&7).
__device__ __forceinline__ void gemm64k64_core(const u16* __restrict__ A,
                                               const u16* __restrict__ W,
                                               int m0, int n0,
                                               u16 (*As)[64 * 64],
                                               u16 (*Bs)[128 * 64],
                                               f32x4 acc[2][4]) {
  const int tid = threadIdx.x;
  const int lane = tid & 63, wave = tid >> 6;
  const int wm = wave >> 1, wn = wave & 1;
  const int lr = lane & 15, lg = lane >> 4;

  auto stage = [&](int buf, int kt) {
#pragma unroll
    for (int i = 0; i < 2; i++) {  // A tile: 64 rows x 64 elems (128-B rows)
      const int idx = i * 256 + tid;
      const int r = idx >> 3, c = idx & 7;
      GLOAD16(A + (size_t)(m0 + r) * 1024 + kt * 64 + (c ^ (r & 7)) * 8,
              &As[buf][idx * 8]);
    }
#pragma unroll
    for (int i = 0; i < 4; i++) {  // W tile: 128 rows x 64 elems
      const int idx = i * 256 + tid;
      const int r = idx >> 3, c = idx & 7;
      GLOAD16(W + (size_t)(n0 + r) * 1024 + kt * 64 + (c ^ (r & 7)) * 8,
              &Bs[buf][idx * 8]);
    }
  };

  stage(0, 0);
  int cur = 0;
  for (int kt = 0; kt < 16; ++kt) {
    __syncthreads();  // stage(kt) landed (vmcnt) + prior reads done (lgkm)
    if (kt + 1 < 16) stage(cur ^ 1, kt + 1);
#pragma unroll
    for (int ks = 0; ks < 2; ks++) {
      const int co = ((ks * 4 + lg) ^ (lr & 7)) * 8;  // swizzled chunk
      bf16x8 af[2], bfr[4];
#pragma unroll
      for (int m = 0; m < 2; m++)
        af[m] = *(const bf16x8*)&As[cur][(wm * 32 + m * 16 + lr) * 64 + co];
#pragma unroll
      for (int n = 0; n < 4; n++)
        bfr[n] = *(const bf16x8*)&Bs[cur][(wn * 64 + n * 16 + lr) * 64 + co];
#pragma unroll
      for (int m = 0; m < 2; m++)
#pragma unroll
        for (int n = 0; n < 4; n++)
          acc[m][n] = MFMA16(af[m], bfr[n], acc[m][n]);
    }
    cur ^= 1;
  }
}

// -------------------------------------------------------- QKV projections
// grid (64, 8, 3) = 1536 blocks; 48 KB LDS -> 3 blocks/CU. R16-proven.
__global__ __launch_bounds__(256, 3) void qkv_gemm(
    const u16* __restrict__ xn, const u16* __restrict__ Wall,
    const float* __restrict__ bQ, const float* __restrict__ bK,
    const float* __restrict__ bV, u16* __restrict__ Qb, u16* __restrict__ Kb,
    u16* __restrict__ VTb) {
  __shared__ u16 As[2][64 * 64];
  __shared__ u16 Bs[2][128 * 64];
  const int z = blockIdx.z;
  const u16* W = Wall + ((size_t)z << 20);
  const float* bias = (z == 0) ? bQ : (z == 1) ? bK : bV;
  const float bscale = (z == 0) ? QSCALE : 1.0f;
  const int m0 = blockIdx.x * 64, n0 = blockIdx.y * 128;
  f32x4 acc[2][4] = {};
  gemm64k64_core(xn, W, m0, n0, As, Bs, acc);

  const int lane = threadIdx.x & 63, wave = threadIdx.x >> 6;
  const int wm = wave >> 1, wn = wave & 1, lr = lane & 15, lg = lane >> 4;
  if (z == 2) {
#pragma unroll
    for (int n = 0; n < 4; n++) {
      const int col = n0 + wn * 64 + n * 16 + lr;
      const float bv = bias[col];
      const int hh = col >> 6, d = col & 63;
#pragma unroll
      for (int m = 0; m < 2; m++) {
        const int rb = m0 + wm * 32 + m * 16 + lg * 4;
#pragma unroll
        for (int j = 0; j < 4; j++) {
          const int row = rb + j;
          const int bb = row >> 11, s = row & 2047;
          VTb[(((size_t)(bb * 16 + hh) * 64 + d) << 11) + s] =
              f2bf(acc[m][n][j] + bv);
        }
      }
    }
  } else {
    u16* o = (z == 0) ? Qb : Kb;
#pragma unroll
    for (int n = 0; n < 4; n++) {
      const int col = n0 + wn * 64 + n * 16 + lr;
      const float bv = bias[col] * bscale;
#pragma unroll
      for (int m = 0; m < 2; m++) {
        const int rb = m0 + wm * 32 + m * 16 + lg * 4;
#pragma unroll
        for (int j = 0; j < 4; j++)
          o[(size_t)(rb + j) * 1024 + col] = f2bf(acc[m][n][j] + bv);
      }
    }
  }
}

// ------------------------------------------------------- output projection
// R17: ported to the R16-proven BK=64 fat-step core. grid (64,8) = 2/CU.
__global__ __launch_bounds__(256, 3) void o_gemm(const u16* __restrict__ A,
                                                 const u16* __restrict__ W,
                                                 const float* __restrict__ bias,
                                                 float* __restrict__ out) {
  __shared__ u16 As[2][64 * 64];
  __shared__ u16 Bs[2][128 * 64];
  const int m0 = blockIdx.x * 64, n0 = blockIdx.y * 128;
  f32x4 acc[2][4] = {};
  gemm64k64_core(A, W, m0, n0, As, Bs, acc);
  const int lane = threadIdx.x & 63, wave = threadIdx.x >> 6;
  const int wm = wave >> 1, wn = wave & 1, lr = lane & 15, lg = lane >> 4;
#pragma unroll
  for (int n = 0; n < 4; n++) {
    const int col = n0 + wn * 64 + n * 16 + lr;
    const float bv = bias[col];
#pragma unroll
    for (int m = 0; m < 2; m++) {
      const int rb = m0 + wm * 32 + m * 16 + lg * 4;
#pragma unroll
      for (int j = 0; j < 4; j++)
        out[(size_t)(rb + j) * 1024 + col] = acc[m][n][j] + bv;
    }
  }
}

// --------------------------------------------------------- flash attention
// R17: q-groups 2 -> 4 (64 q-rows/wave, 256 q-rows/block). Each K/V LDS
// fragment read now feeds 4 MFMAs (was 2): LDS reads per unit work halved
// (the dominant pipe, ~27 us of 48). grid (8,32) = 256 blocks = 1/CU;
// 4 waves = 1 wave/SIMD; dbuf intra-block overlap retained. VGPR ~270
// (s[4][8] live in QK^T) -- launch_bounds(256,1) gives 512 headroom.
// All other techniques R15-proven (swapped QK^T, in-register P, half-tile
// V, l-sum via ones-MFMA, setprio).
__global__ __launch_bounds__(256, 1) void attn_kernel(
    const u16* __restrict__ Qb, const u16* __restrict__ Kb,
    const u16* __restrict__ VTb, u16* __restrict__ Hb) {
  __shared__ u16 Ks[2][128 * 64];     // [kv][d], 128-B rows
  __shared__ u16 Vs[2][2][64 * 64];   // [half][d][kv-half], 128-B rows
  const int tid = threadIdx.x;
  const int wave = tid >> 6, lane = tid & 63;
  const int lr = lane & 15, lg = lane >> 4;
  const int qb = blockIdx.x, bh = blockIdx.y;
  const int b = bh >> 4, h = bh & 15;

  // Q strips: 4 groups of 16 rows, held in registers (prescaled by log2e/8)
  bf16x8 aq[4][2];
#pragma unroll
  for (int qg = 0; qg < 4; qg++) {
    const int qrow = b * 2048 + qb * 256 + wave * 64 + qg * 16 + lr;
    const u16* qsrc = Qb + (size_t)qrow * 1024 + h * 64 + lg * 8;
    aq[qg][0] = *(const bf16x8*)qsrc;
    aq[qg][1] = *(const bf16x8*)(qsrc + 32);
  }

  f32x4 oacc[4][4] = {};
  f32x4 lacc[4] = {};  // row-sums of P, accumulated on the matrix pipe
  const ui4 ones_u = {0x3f803f80u, 0x3f803f80u, 0x3f803f80u, 0x3f803f80u};
  const bf16x8 ones = __builtin_bit_cast(bf16x8, ones_u);

  auto stage = [&](int buf, int kt) {
#pragma unroll
    for (int i = 0; i < 4; i++) {  // K tile: 128 rows x 64 d, 128-B rows
      const int idx = i * 256 + tid;
      const int r = idx >> 3, c = idx & 7;
      GLOAD16(Kb + (size_t)(b * 2048 + kt * 128 + r) * 1024 + h * 64 +
                  (c ^ (r & 7)) * 8,
              &Ks[buf][idx * 8]);
    }
#pragma unroll
    for (int half = 0; half < 2; half++) {
#pragma unroll
      for (int i = 0; i < 2; i++) {
        const int jdx = i * 256 + tid;
        const int r = jdx >> 3, lc = jdx & 7;
        GLOAD16(VTb + (size_t)(bh * 64 + r) * 2048 + kt * 128 +
                    (half * 8 + (lc ^ (r & 7))) * 8,
                &Vs[buf][half][jdx * 8]);
      }
    }
  };

  // softmax-lite + pack for one q-group (all indices compile-time)
  auto softpack = [&](f32x4 (&s)[8], ui4 (&pf)[4]) {
#pragma unroll
    for (int n = 0; n < 8; n++)
#pragma unroll
      for (int j = 0; j < 4; j++)
        s[n][j] = __builtin_amdgcn_exp2f(s[n][j]);
    unsigned int w[8][2];
#pragma unroll
    for (int n = 0; n < 8; n++) {
      asm("v_cvt_pk_bf16_f32 %0, %1, %2"
          : "=v"(w[n][0])
          : "v"(s[n][0]), "v"(s[n][1]));
      asm("v_cvt_pk_bf16_f32 %0, %1, %2"
          : "=v"(w[n][1])
          : "v"(s[n][2]), "v"(s[n][3]));
    }
#pragma unroll
    for (int ks = 0; ks < 4; ks++) {
      unsigned int pw[4];
#pragma unroll
      for (int rp = 0; rp < 2; rp++) {
        unsigned int a = w[2 * ks][rp], bb = w[2 * ks + 1][rp];
        asm("v_permlane32_swap_b32 %0, %1" : "+v"(a), "+v"(bb));
        asm("v_permlane16_swap_b32 %0, %1" : "+v"(a), "+v"(bb));
        pw[rp] = a;
        pw[2 + rp] = bb;
      }
      pf[ks] = (ui4){pw[0], pw[1], pw[2], pw[3]};
    }
  };

  stage(0, 0);
  int cur = 0;
  for (int kt = 0; kt < 16; ++kt) {
    __syncthreads();
    if (kt + 1 < 16) stage(cur ^ 1, kt + 1);

    // S^T = K Q^T for all 4 q-groups; K fragments read once, used 4x
    f32x4 s0[8], s1[8], s2[8], s3[8];
#pragma unroll
    for (int n = 0; n < 8; n++) {
      s0[n] = (f32x4){0.f, 0.f, 0.f, 0.f};
      s1[n] = (f32x4){0.f, 0.f, 0.f, 0.f};
      s2[n] = (f32x4){0.f, 0.f, 0.f, 0.f};
      s3[n] = (f32x4){0.f, 0.f, 0.f, 0.f};
    }
    __builtin_amdgcn_s_setprio(1);
#pragma unroll
    for (int n = 0; n < 8; n++) {
      const int row = n * 16 + lr;
#pragma unroll
      for (int ks = 0; ks < 2; ks++) {
        const int byo = (ks * 64 + lg * 16) ^ ((row & 7) << 4);
        const bf16x8 kfr = *(const bf16x8*)&Ks[cur][row * 64 + (byo >> 1)];
        s0[n] = MFMA16(kfr, aq[0][ks], s0[n]);
        s1[n] = MFMA16(kfr, aq[1][ks], s1[n]);
        s2[n] = MFMA16(kfr, aq[2][ks], s2[n]);
        s3[n] = MFMA16(kfr, aq[3][ks], s3[n]);
      }
    }
    __builtin_amdgcn_s_setprio(0);

    // P = exp2(S), pack to PV A-fragments (fully in-register)
    ui4 pf0[4], pf1[4], pf2[4], pf3[4];
    softpack(s0, pf0);
    softpack(s1, pf1);
    softpack(s2, pf2);
    softpack(s3, pf3);

    // PV: V fragments read once, used by all 4 q-groups; l via ones-MFMA
    __builtin_amdgcn_s_setprio(1);
#pragma unroll
    for (int ks = 0; ks < 4; ks++) {
      const int half = ks >> 1, ks2 = ks & 1;
      const bf16x8 p0 = __builtin_bit_cast(bf16x8, pf0[ks]);
      const bf16x8 p1 = __builtin_bit_cast(bf16x8, pf1[ks]);
      const bf16x8 p2 = __builtin_bit_cast(bf16x8, pf2[ks]);
      const bf16x8 p3 = __builtin_bit_cast(bf16x8, pf3[ks]);
#pragma unroll
      for (int n = 0; n < 4; n++) {
        const int row = n * 16 + lr;  // d-row, 0..63
        const int ch = ((ks2 * 4 + lg) ^ (row & 7)) * 8;
        const bf16x8 vb = *(const bf16x8*)&Vs[cur][half][row * 64 + ch];
        oacc[0][n] = MFMA16(p0, vb, oacc[0][n]);
        oacc[1][n] = MFMA16(p1, vb, oacc[1][n]);
        oacc[2][n] = MFMA16(p2, vb, oacc[2][n]);
        oacc[3][n] = MFMA16(p3, vb, oacc[3][n]);
      }
      lacc[0] = MFMA16(p0, ones, lacc[0]);
      lacc[1] = MFMA16(p1, ones, lacc[1]);
      lacc[2] = MFMA16(p2, ones, lacc[2]);
      lacc[3] = MFMA16(p3, ones, lacc[3]);
    }
    __builtin_amdgcn_s_setprio(0);
    cur ^= 1;
  }

  // final: lacc[qg][j] is the full row-sum for q-row (lg*4+j) already
#pragma unroll
  for (int qg = 0; qg < 4; qg++) {
    float rl[4];
#pragma unroll
    for (int j = 0; j < 4; j++) rl[j] = 1.0f / lacc[qg][j];
    const int hrow_base = b * 2048 + qb * 256 + wave * 64 + qg * 16 + lg * 4;
#pragma unroll
    for (int n = 0; n < 4; n++) {
      const int col = h * 64 + n * 16 + lr;
#pragma unroll
      for (int j = 0; j < 4; j++) {
        const float val = oacc[qg][n][j] * rl[j];
        Hb[(size_t)(hrow_base + j) * 1024 + col] = f2bf(val);
      }
    }
  }
}

// ------------------------------------------------------------------ launch
extern "C" void kernel_launch(void* const* d_in, const int* in_sizes, int n_in,
                              void* d_out, int out_size, void* d_ws,
                              size_t ws_size, hipStream_t stream) {
  const float* x = (const float*)d_in[0];
  const float* wQ = (const float*)d_in[1];
  const float* bQ = (const float*)d_in[2];
  const float* wK = (const float*)d_in[3];
  const float* bK = (const float*)d_in[4];
  const float* wV = (const float*)d_in[5];
  const float* bV = (const float*)d_in[6];
  const float* wO = (const float*)d_in[7];
  const float* bO = (const float*)d_in[8];
  float* out = (float*)d_out;

  char* ws = (char*)d_ws;
  u16* xn = (u16*)(ws);                       // 8 MiB  [4096][1024]
  u16* Wall = (u16*)(ws + ((size_t)8 << 20)); // 8 MiB  4x[1024][1024]
  u16* Qb = (u16*)(ws + ((size_t)16 << 20));  // 8 MiB  [4096][1024]
  u16* Kb = (u16*)(ws + ((size_t)24 << 20));  // 8 MiB  [4096][1024]
  u16* VTb = (u16*)(ws + ((size_t)32 << 20)); // 8 MiB  [32][64][2048]
  u16* Hb = (u16*)(ws + ((size_t)40 << 20));  // 8 MiB  [4096][1024]

  prep_kernel<<<6144, 256, 0, stream>>>(x, wQ, wK, wV, wO, xn, Wall);
  qkv_gemm<<<dim3(64, 8, 3), 256, 0, stream>>>(xn, Wall, bQ, bK, bV, Qb, Kb,
                                               VTb);
  attn_kernel<<<dim3(8, 32), 256, 0, stream>>>(Qb, Kb, VTb, Hb);
  o_gemm<<<dim3(64, 8), 256, 0, stream>>>(Hb, Wall + ((size_t)3 << 20), bO,
                                          out);
}

// Round 18
// 106.753 us; speedup vs baseline: 1.1421x; 1.1421x over previous
//
#include <hip/hip_runtime.h>
#include <cstdint>
#include <cstddef>

typedef __bf16 bf16x8 __attribute__((ext_vector_type(8)));
typedef float f32x4 __attribute__((ext_vector_type(4)));
typedef unsigned short us4 __attribute__((ext_vector_type(4)));
typedef unsigned short us8 __attribute__((ext_vector_type(8)));
typedef unsigned int ui4 __attribute__((ext_vector_type(4)));
typedef unsigned short u16;

// 0.125 (1/sqrt(Dh)) * log2(e) -- Q prescale so softmax uses raw v_exp_f32 (exp2)
#define QSCALE 0.18033688011112042f

#define MFMA16(a, b, c) __builtin_amdgcn_mfma_f32_16x16x32_bf16((a), (b), (c), 0, 0, 0)
#define GLOAD16(g, l)                                                        \
  __builtin_amdgcn_global_load_lds(                                          \
      (const __attribute__((address_space(1))) void*)(g),                    \
      (__attribute__((address_space(3))) void*)(l), 16, 0, 0)

__device__ __forceinline__ u16 f2bf(float x) {
  unsigned int u = __float_as_uint(x);
  unsigned int r = u + 0x7fffu + ((u >> 16) & 1u);
  return (u16)(r >> 16);
}

// ------------------------------------------------- fused LayerNorm + wprep
// blocks 0..4095: LN row; blocks 4096..6143: weight convert (4 mats x 512).
__global__ __launch_bounds__(256) void prep_kernel(
    const float* __restrict__ x, const float* __restrict__ wq,
    const float* __restrict__ wk, const float* __restrict__ wv,
    const float* __restrict__ wo, u16* __restrict__ xn,
    u16* __restrict__ wdst) {
  const int bid = blockIdx.x;
  const int t = threadIdx.x;
  if (bid < 4096) {
    const int row = bid;
    const float* xr = x + (size_t)row * 1024;
    float4 v = *(const float4*)(xr + t * 4);
    float s = v.x + v.y + v.z + v.w;
    float s2 = v.x * v.x + v.y * v.y + v.z * v.z + v.w * v.w;
#pragma unroll
    for (int o = 32; o >= 1; o >>= 1) {
      s += __shfl_xor(s, o);
      s2 += __shfl_xor(s2, o);
    }
    __shared__ float red[8];
    const int wv_ = t >> 6, ln = t & 63;
    if (ln == 0) {
      red[wv_] = s;
      red[4 + wv_] = s2;
    }
    __syncthreads();
    s = red[0] + red[1] + red[2] + red[3];
    s2 = red[4] + red[5] + red[6] + red[7];
    const float mu = s * (1.0f / 1024.0f);
    float var = (s2 - 1024.0f * mu * mu) * (1.0f / 1023.0f);
    var = fmaxf(var, 0.0f);
    const float inv = 1.0f / (sqrtf(var) + 1e-6f);
    us4 o;
    o.x = f2bf((v.x - mu) * inv);
    o.y = f2bf((v.y - mu) * inv);
    o.z = f2bf((v.z - mu) * inv);
    o.w = f2bf((v.w - mu) * inv);
    *(us4*)(xn + (size_t)row * 1024 + t * 4) = o;
  } else {
    const int wid = bid - 4096;
    const int mat = wid >> 9, xi = wid & 511;
    const float* src = (mat == 0) ? wq : (mat == 1) ? wk : (mat == 2) ? wv : wo;
    const float sc = (mat == 0) ? QSCALE : 1.0f;
    u16* d = wdst + ((size_t)mat << 20);
    const size_t i = ((size_t)xi * 256 + t) * 8;
    float4 a = *(const float4*)(src + i);
    float4 b = *(const float4*)(src + i + 4);
    us8 o;
    o[0] = f2bf(a.x * sc);
    o[1] = f2bf(a.y * sc);
    o[2] = f2bf(a.z * sc);
    o[3] = f2bf(a.w * sc);
    o[4] = f2bf(b.x * sc);
    o[5] = f2bf(b.y * sc);
    o[6] = f2bf(b.z * sc);
    o[7] = f2bf(b.w * sc);
    *(us8*)(d + i) = o;
  }
}

// ------------------------------------------- GEMM core (R16-proven BK=64)
// C[64x128] = A[64xK] * W[128xK]^T. Fat-step dbuf-2 + __syncthreads:
// 16 steps of 16 MFMAs + 12 ds_reads per wave. 48 KB LDS.
// Swizzle: 128-B rows, source chunk c^(r&7), read chunk (ks*4+lg)^(lr&7).
__device__ __forceinline__ void gemm64k64_core(const u16* __restrict__ A,
                                               const u16* __restrict__ W,
                                               int m0, int n0,
                                               u16 (*As)[64 * 64],
                                               u16 (*Bs)[128 * 64],
                                               f32x4 acc[2][4]) {
  const int tid = threadIdx.x;
  const int lane = tid & 63, wave = tid >> 6;
  const int wm = wave >> 1, wn = wave & 1;
  const int lr = lane & 15, lg = lane >> 4;

  auto stage = [&](int buf, int kt) {
#pragma unroll
    for (int i = 0; i < 2; i++) {  // A tile: 64 rows x 64 elems (128-B rows)
      const int idx = i * 256 + tid;
      const int r = idx >> 3, c = idx & 7;
      GLOAD16(A + (size_t)(m0 + r) * 1024 + kt * 64 + (c ^ (r & 7)) * 8,
              &As[buf][idx * 8]);
    }
#pragma unroll
    for (int i = 0; i < 4; i++) {  // W tile: 128 rows x 64 elems
      const int idx = i * 256 + tid;
      const int r = idx >> 3, c = idx & 7;
      GLOAD16(W + (size_t)(n0 + r) * 1024 + kt * 64 + (c ^ (r & 7)) * 8,
              &Bs[buf][idx * 8]);
    }
  };

  stage(0, 0);
  int cur = 0;
  for (int kt = 0; kt < 16; ++kt) {
    __syncthreads();  // stage(kt) landed (vmcnt) + prior reads done (lgkm)
    if (kt + 1 < 16) stage(cur ^ 1, kt + 1);
#pragma unroll
    for (int ks = 0; ks < 2; ks++) {
      const int co = ((ks * 4 + lg) ^ (lr & 7)) * 8;  // swizzled chunk
      bf16x8 af[2], bfr[4];
#pragma unroll
      for (int m = 0; m < 2; m++)
        af[m] = *(const bf16x8*)&As[cur][(wm * 32 + m * 16 + lr) * 64 + co];
#pragma unroll
      for (int n = 0; n < 4; n++)
        bfr[n] = *(const bf16x8*)&Bs[cur][(wn * 64 + n * 16 + lr) * 64 + co];
#pragma unroll
      for (int m = 0; m < 2; m++)
#pragma unroll
        for (int n = 0; n < 4; n++)
          acc[m][n] = MFMA16(af[m], bfr[n], acc[m][n]);
    }
    cur ^= 1;
  }
}

// -------------------------------------------------------- QKV projections
// grid (64, 8, 3) = 1536 blocks; 48 KB LDS -> 3 blocks/CU. R16-proven.
__global__ __launch_bounds__(256, 3) void qkv_gemm(
    const u16* __restrict__ xn, const u16* __restrict__ Wall,
    const float* __restrict__ bQ, const float* __restrict__ bK,
    const float* __restrict__ bV, u16* __restrict__ Qb, u16* __restrict__ Kb,
    u16* __restrict__ VTb) {
  __shared__ u16 As[2][64 * 64];
  __shared__ u16 Bs[2][128 * 64];
  const int z = blockIdx.z;
  const u16* W = Wall + ((size_t)z << 20);
  const float* bias = (z == 0) ? bQ : (z == 1) ? bK : bV;
  const float bscale = (z == 0) ? QSCALE : 1.0f;
  const int m0 = blockIdx.x * 64, n0 = blockIdx.y * 128;
  f32x4 acc[2][4] = {};
  gemm64k64_core(xn, W, m0, n0, As, Bs, acc);

  const int lane = threadIdx.x & 63, wave = threadIdx.x >> 6;
  const int wm = wave >> 1, wn = wave & 1, lr = lane & 15, lg = lane >> 4;
  if (z == 2) {
#pragma unroll
    for (int n = 0; n < 4; n++) {
      const int col = n0 + wn * 64 + n * 16 + lr;
      const float bv = bias[col];
      const int hh = col >> 6, d = col & 63;
#pragma unroll
      for (int m = 0; m < 2; m++) {
        const int rb = m0 + wm * 32 + m * 16 + lg * 4;
#pragma unroll
        for (int j = 0; j < 4; j++) {
          const int row = rb + j;
          const int bb = row >> 11, s = row & 2047;
          VTb[(((size_t)(bb * 16 + hh) * 64 + d) << 11) + s] =
              f2bf(acc[m][n][j] + bv);
        }
      }
    }
  } else {
    u16* o = (z == 0) ? Qb : Kb;
#pragma unroll
    for (int n = 0; n < 4; n++) {
      const int col = n0 + wn * 64 + n * 16 + lr;
      const float bv = bias[col] * bscale;
#pragma unroll
      for (int m = 0; m < 2; m++) {
        const int rb = m0 + wm * 32 + m * 16 + lg * 4;
#pragma unroll
        for (int j = 0; j < 4; j++)
          o[(size_t)(rb + j) * 1024 + col] = f2bf(acc[m][n][j] + bv);
      }
    }
  }
}

// ------------------------------------------------------- output projection
// BK=64 fat-step core (kept from R17; never in top-5 = neutral-or-better).
__global__ __launch_bounds__(256, 3) void o_gemm(const u16* __restrict__ A,
                                                 const u16* __restrict__ W,
                                                 const float* __restrict__ bias,
                                                 float* __restrict__ out) {
  __shared__ u16 As[2][64 * 64];
  __shared__ u16 Bs[2][128 * 64];
  const int m0 = blockIdx.x * 64, n0 = blockIdx.y * 128;
  f32x4 acc[2][4] = {};
  gemm64k64_core(A, W, m0, n0, As, Bs, acc);
  const int lane = threadIdx.x & 63, wave = threadIdx.x >> 6;
  const int wm = wave >> 1, wn = wave & 1, lr = lane & 15, lg = lane >> 4;
#pragma unroll
  for (int n = 0; n < 4; n++) {
    const int col = n0 + wn * 64 + n * 16 + lr;
    const float bv = bias[col];
#pragma unroll
    for (int m = 0; m < 2; m++) {
      const int rb = m0 + wm * 32 + m * 16 + lg * 4;
#pragma unroll
      for (int j = 0; j < 4; j++)
        out[(size_t)(rb + j) * 1024 + col] = acc[m][n][j] + bv;
    }
  }
}

// --------------------------------------------------------- flash attention
// R16-PROVEN (48.2 us, MfmaUtil 31%): grid (16,32), 4 waves/block, 32
// q-rows/wave (2 q-groups), KVBLK=128, swapped QK^T + in-register P
// redistribution, dbuf-2 + __syncthreads, setprio, l-sum via ones-MFMA,
// V in two [64][64] half-tiles (conflict-free). (R17's 4-qg variant
// regressed to 64.6 us: 1 block/CU -> 1 wave/SIMD, nothing to overlap
// the softpack VALU chain; occupancy 10%, compiler serialized s-arrays.)
__global__ __launch_bounds__(256, 2) void attn_kernel(
    const u16* __restrict__ Qb, const u16* __restrict__ Kb,
    const u16* __restrict__ VTb, u16* __restrict__ Hb) {
  __shared__ u16 Ks[2][128 * 64];     // [kv][d], 128-B rows
  __shared__ u16 Vs[2][2][64 * 64];   // [half][d][kv-half], 128-B rows
  const int tid = threadIdx.x;
  const int wave = tid >> 6, lane = tid & 63;
  const int lr = lane & 15, lg = lane >> 4;
  const int qb = blockIdx.x, bh = blockIdx.y;
  const int b = bh >> 4, h = bh & 15;

  // Q strips: 2 groups of 16 rows, held in registers (prescaled by log2e/8)
  bf16x8 aq[2][2];
#pragma unroll
  for (int qg = 0; qg < 2; qg++) {
    const int qrow = b * 2048 + qb * 128 + wave * 32 + qg * 16 + lr;
    const u16* qsrc = Qb + (size_t)qrow * 1024 + h * 64 + lg * 8;
    aq[qg][0] = *(const bf16x8*)qsrc;
    aq[qg][1] = *(const bf16x8*)(qsrc + 32);
  }

  f32x4 oacc[2][4] = {};
  f32x4 lacc[2] = {};  // row-sums of P, accumulated on the matrix pipe
  const ui4 ones_u = {0x3f803f80u, 0x3f803f80u, 0x3f803f80u, 0x3f803f80u};
  const bf16x8 ones = __builtin_bit_cast(bf16x8, ones_u);

  auto stage = [&](int buf, int kt) {
#pragma unroll
    for (int i = 0; i < 4; i++) {  // K tile: 128 rows x 64 d, 128-B rows
      const int idx = i * 256 + tid;
      const int r = idx >> 3, c = idx & 7;
      GLOAD16(Kb + (size_t)(b * 2048 + kt * 128 + r) * 1024 + h * 64 +
                  (c ^ (r & 7)) * 8,
              &Ks[buf][idx * 8]);
    }
    // V half-tiles: [64 d-rows][64 kv], 128-B rows; linear lane-contiguous
    // LDS dest (rule 21), inverse-swizzled global source within each half.
#pragma unroll
    for (int half = 0; half < 2; half++) {
#pragma unroll
      for (int i = 0; i < 2; i++) {
        const int jdx = i * 256 + tid;
        const int r = jdx >> 3, lc = jdx & 7;
        GLOAD16(VTb + (size_t)(bh * 64 + r) * 2048 + kt * 128 +
                    (half * 8 + (lc ^ (r & 7))) * 8,
                &Vs[buf][half][jdx * 8]);
      }
    }
  };

  // softmax-lite + pack for one q-group (all indices compile-time)
  auto softpack = [&](f32x4 (&s)[8], ui4 (&pf)[4]) {
#pragma unroll
    for (int n = 0; n < 8; n++)
#pragma unroll
      for (int j = 0; j < 4; j++)
        s[n][j] = __builtin_amdgcn_exp2f(s[n][j]);
    unsigned int w[8][2];
#pragma unroll
    for (int n = 0; n < 8; n++) {
      asm("v_cvt_pk_bf16_f32 %0, %1, %2"
          : "=v"(w[n][0])
          : "v"(s[n][0]), "v"(s[n][1]));
      asm("v_cvt_pk_bf16_f32 %0, %1, %2"
          : "=v"(w[n][1])
          : "v"(s[n][2]), "v"(s[n][3]));
    }
#pragma unroll
    for (int ks = 0; ks < 4; ks++) {
      unsigned int pw[4];
#pragma unroll
      for (int rp = 0; rp < 2; rp++) {
        unsigned int a = w[2 * ks][rp], bb = w[2 * ks + 1][rp];
        asm("v_permlane32_swap_b32 %0, %1" : "+v"(a), "+v"(bb));
        asm("v_permlane16_swap_b32 %0, %1" : "+v"(a), "+v"(bb));
        pw[rp] = a;
        pw[2 + rp] = bb;
      }
      pf[ks] = (ui4){pw[0], pw[1], pw[2], pw[3]};
    }
  };

  stage(0, 0);
  int cur = 0;
  for (int kt = 0; kt < 16; ++kt) {
    __syncthreads();
    if (kt + 1 < 16) stage(cur ^ 1, kt + 1);

    // S^T = K Q^T for both q-groups; K fragments read once, used twice
    f32x4 s0[8], s1[8];
#pragma unroll
    for (int n = 0; n < 8; n++) {
      s0[n] = (f32x4){0.f, 0.f, 0.f, 0.f};
      s1[n] = (f32x4){0.f, 0.f, 0.f, 0.f};
    }
    __builtin_amdgcn_s_setprio(1);
#pragma unroll
    for (int n = 0; n < 8; n++) {
      const int row = n * 16 + lr;
#pragma unroll
      for (int ks = 0; ks < 2; ks++) {
        const int byo = (ks * 64 + lg * 16) ^ ((row & 7) << 4);
        const bf16x8 kfr = *(const bf16x8*)&Ks[cur][row * 64 + (byo >> 1)];
        s0[n] = MFMA16(kfr, aq[0][ks], s0[n]);
        s1[n] = MFMA16(kfr, aq[1][ks], s1[n]);
      }
    }
    __builtin_amdgcn_s_setprio(0);

    // P = exp2(S), pack to PV A-fragments (fully in-register)
    ui4 pf0[4], pf1[4];
    softpack(s0, pf0);
    softpack(s1, pf1);

    // PV: V fragments read once, used by both q-groups; l-sum via ones-MFMA
    __builtin_amdgcn_s_setprio(1);
#pragma unroll
    for (int ks = 0; ks < 4; ks++) {
      const int half = ks >> 1, ks2 = ks & 1;
      const bf16x8 p0 = __builtin_bit_cast(bf16x8, pf0[ks]);
      const bf16x8 p1 = __builtin_bit_cast(bf16x8, pf1[ks]);
#pragma unroll
      for (int n = 0; n < 4; n++) {
        const int row = n * 16 + lr;  // d-row, 0..63
        const int ch = ((ks2 * 4 + lg) ^ (row & 7)) * 8;
        const bf16x8 vb = *(const bf16x8*)&Vs[cur][half][row * 64 + ch];
        oacc[0][n] = MFMA16(p0, vb, oacc[0][n]);
        oacc[1][n] = MFMA16(p1, vb, oacc[1][n]);
      }
      lacc[0] = MFMA16(p0, ones, lacc[0]);
      lacc[1] = MFMA16(p1, ones, lacc[1]);
    }
    __builtin_amdgcn_s_setprio(0);
    cur ^= 1;
  }

  // final: lacc[qg][j] is the full row-sum for q-row (lg*4+j) already
#pragma unroll
  for (int qg = 0; qg < 2; qg++) {
    float rl[4];
#pragma unroll
    for (int j = 0; j < 4; j++) rl[j] = 1.0f / lacc[qg][j];
    const int hrow_base = b * 2048 + qb * 128 + wave * 32 + qg * 16 + lg * 4;
#pragma unroll
    for (int n = 0; n < 4; n++) {
      const int col = h * 64 + n * 16 + lr;
#pragma unroll
      for (int j = 0; j < 4; j++) {
        const float val = oacc[qg][n][j] * rl[j];
        Hb[(size_t)(hrow_base + j) * 1024 + col] = f2bf(val);
      }
    }
  }
}

// ------------------------------------------------------------------ launch
extern "C" void kernel_launch(void* const* d_in, const int* in_sizes, int n_in,
                              void* d_out, int out_size, void* d_ws,
                              size_t ws_size, hipStream_t stream) {
  const float* x = (const float*)d_in[0];
  const float* wQ = (const float*)d_in[1];
  const float* bQ = (const float*)d_in[2];
  const float* wK = (const float*)d_in[3];
  const float* bK = (const float*)d_in[4];
  const float* wV = (const float*)d_in[5];
  const float* bV = (const float*)d_in[6];
  const float* wO = (const float*)d_in[7];
  const float* bO = (const float*)d_in[8];
  float* out = (float*)d_out;

  char* ws = (char*)d_ws;
  u16* xn = (u16*)(ws);                       // 8 MiB  [4096][1024]
  u16* Wall = (u16*)(ws + ((size_t)8 << 20)); // 8 MiB  4x[1024][1024]
  u16* Qb = (u16*)(ws + ((size_t)16 << 20));  // 8 MiB  [4096][1024]
  u16* Kb = (u16*)(ws + ((size_t)24 << 20));  // 8 MiB  [4096][1024]
  u16* VTb = (u16*)(ws + ((size_t)32 << 20)); // 8 MiB  [32][64][2048]
  u16* Hb = (u16*)(ws + ((size_t)40 << 20));  // 8 MiB  [4096][1024]

  prep_kernel<<<6144, 256, 0, stream>>>(x, wQ, wK, wV, wO, xn, Wall);
  qkv_gemm<<<dim3(64, 8, 3), 256, 0, stream>>>(xn, Wall, bQ, bK, bV, Qb, Kb,
                                               VTb);
  attn_kernel<<<dim3(16, 32), 256, 0, stream>>>(Qb, Kb, VTb, Hb);
  o_gemm<<<dim3(64, 8), 256, 0, stream>>>(Hb, Wall + ((size_t)3 << 20), bO,
                                          out);
}